// Round 14
// baseline (443.578 us; speedup 1.0000x reference)
//
#include <hip/hip_runtime.h>
#include <hip/hip_bf16.h>
#include <cmath>

typedef __hip_bfloat16 bf16;
typedef __attribute__((ext_vector_type(8))) short short8;   // 8 bf16 (4 VGPRs)
typedef __attribute__((ext_vector_type(4))) float f32x4;

#define SEQ   2048
#define DIMX  512
#define DIM2X 1024
#define NHEADS 8
#define HDIM  128
#define EPSF  1e-5f
#define PADROWS 2051   // 3 zero rows + 2048 per batch

__device__ __forceinline__ float b2f(bf16 v) { return __bfloat162float(v); }
__device__ __forceinline__ bf16 f2b(float f) { return __float2bfloat16(f); }
__device__ __forceinline__ unsigned short f2bu(float f) { bf16 t = __float2bfloat16(f); return *(unsigned short*)&t; }

// async global->LDS, 16B per lane. LDS dest must be linear in lane order (wave base + lane*16).
__device__ __forceinline__ void gl16(const bf16* g, bf16* l) {
  __builtin_amdgcn_global_load_lds((const __attribute__((address_space(1))) void*)g,
                                   (__attribute__((address_space(3))) void*)l, 16, 0, 0);
}

// ---------------- LayerNorm: one wave per row of 512 (fp32 in, bf16 out) ----------------
__global__ void __launch_bounds__(256) k_layernorm(const float* __restrict__ x,
                                                   const float* __restrict__ w,
                                                   const float* __restrict__ b,
                                                   bf16* __restrict__ out) {
  int row  = blockIdx.x * 4 + (threadIdx.x >> 6);
  int lane = threadIdx.x & 63;
  const float* xr = x + (size_t)row * DIMX;
  float v[8]; float s = 0.f, sq = 0.f;
#pragma unroll
  for (int i = 0; i < 8; i++) {
    float f = xr[lane + i * 64];
    v[i] = f; s += f; sq += f * f;
  }
#pragma unroll
  for (int off = 32; off; off >>= 1) { s += __shfl_xor(s, off); sq += __shfl_xor(sq, off); }
  float mu  = s * (1.f / DIMX);
  float var = sq * (1.f / DIMX) - mu * mu;
  float rs  = rsqrtf(var + EPSF);
  bf16* o = out + (size_t)row * DIMX;
#pragma unroll
  for (int i = 0; i < 8; i++) {
    int c = lane + i * 64;
    o[c] = f2b((v[i] - mu) * rs * w[c] + b[c]);
  }
}

// ---------------- fused weight cast+transpose: dst = sel-th of {W0,W1,W2} ----------------
__global__ void __launch_bounds__(256) k_castT3(const float* __restrict__ W0,
                                                const float* __restrict__ W1,
                                                const float* __restrict__ W2,
                                                bf16* __restrict__ WT,
                                                int K, int N, int innerZ, int gW, int gT) {
  __shared__ float t[32][33];
  const int z = blockIdx.z;
  const int sel = z / innerZ, zz = z % innerZ;
  const float* W = (sel == 0 ? W0 : sel == 1 ? W1 : W2) + (size_t)zz * gW;
  bf16* T = WT + (size_t)(sel * innerZ + zz) * gT;
  const int k0 = blockIdx.y * 32, n0 = blockIdx.x * 32;
  const int r = threadIdx.x >> 5, c = threadIdx.x & 31;
#pragma unroll
  for (int i = 0; i < 4; i++)
    t[r + i * 8][c] = W[(size_t)(k0 + r + i * 8) * N + n0 + c];
  __syncthreads();
#pragma unroll
  for (int i = 0; i < 4; i++)
    T[(size_t)(n0 + r + i * 8) * K + k0 + c] = f2b(t[c][r + i * 8]);
}

// ---------------- conv weight reshape (coalesced): thread = one (o,i) ----------------
__global__ void __launch_bounds__(256) k_convwT(const float* __restrict__ cw, bf16* __restrict__ wc) {
  int idx = blockIdx.x * 256 + threadIdx.x;     // (o,i)
  int o = idx >> 10, i = idx & 1023;
  float4 v = *(const float4*)(cw + (size_t)idx * 4);
  size_t base = (size_t)o * 4096 + i;
  wc[base]        = f2b(v.x);
  wc[base + 1024] = f2b(v.y);
  wc[base + 2048] = f2b(v.z);
  wc[base + 3072] = f2b(v.w);
}

// ---------------- zero the 3 pad rows before each batch of padded A ----------------
__global__ void __launch_bounds__(256) k_zeropad(bf16* __restrict__ p) {
  int idx = blockIdx.x * 256 + threadIdx.x;     // 6144 total
  int b = idx / 3072, off = idx % 3072;
  p[(size_t)b * PADROWS * DIM2X + off] = f2b(0.f);
}

// ---------------- GEMM body: 128x64 block, 4 waves, BK=64, 3-buffer counted pipeline ----------------
__device__ __forceinline__ void mgemm_body(const bf16* A, int lda, const bf16* WT,
                                           const float* bias, void* Cv, const float* xres,
                                           int ldc, int K, int ACT, int STORE, int APAD,
                                           size_t coff, int bm, int bn) {
  __shared__ __align__(16) bf16 smA[3][128 * 64];
  __shared__ __align__(16) bf16 smB[3][64 * 64];
  const int tid  = threadIdx.x;
  const int lane = tid & 63;
  const int w = tid >> 6, wy = w >> 1, wx = w & 1;
  const int col = lane & 15, quad = lane >> 4;

  const int r8 = tid >> 3, c8i = tid & 7;
  const int swz = (c8i ^ (r8 & 7)) * 8;       // (r8+p*32)&7 == r8&7
  const bf16* gA[4];
#pragma unroll
  for (int p = 0; p < 4; p++) {
    int ra = bm + r8 + p * 32;
    if (APAD) ra += (ra >> 11) * 3 + 3;
    gA[p] = A + (size_t)ra * lda + swz;
  }
  const bf16* gB[2];
#pragma unroll
  for (int p = 0; p < 2; p++)
    gB[p] = WT + (size_t)(bn + r8 + p * 32) * K + swz;

  f32x4 acc[4][2];
#pragma unroll
  for (int a = 0; a < 4; a++)
#pragma unroll
    for (int b = 0; b < 2; b++) acc[a][b] = (f32x4){0.f, 0.f, 0.f, 0.f};

  const int nsteps = K >> 6;                  // all K here are multiples of 64, nsteps >= 4

#define GSTAGE(buf, k0s)                                                       \
  do {                                                                         \
    bf16* dA = &smA[buf][tid * 8];                                             \
    gl16(gA[0] + (k0s), dA);                                                   \
    gl16(gA[1] + (k0s), dA + 2048);                                            \
    gl16(gA[2] + (k0s), dA + 4096);                                            \
    gl16(gA[3] + (k0s), dA + 6144);                                            \
    bf16* dB = &smB[buf][tid * 8];                                             \
    gl16(gB[0] + (k0s), dB);                                                   \
    gl16(gB[1] + (k0s), dB + 2048);                                            \
  } while (0)

  GSTAGE(0, 0);
  GSTAGE(1, 64);
  int buf = 0;
  for (int s = 0; s < nsteps; ++s) {
    if (s + 1 < nsteps) asm volatile("s_waitcnt vmcnt(6)" ::: "memory");
    else                asm volatile("s_waitcnt vmcnt(0)" ::: "memory");
    __builtin_amdgcn_s_barrier();
    if (s + 2 < nsteps) {
      int nb = buf + 2; if (nb >= 3) nb -= 3;
      GSTAGE(nb, (s + 2) * 64);
    }
    asm volatile("" ::: "memory");
    const bf16* bA = smA[buf];
    const bf16* bB = smB[buf];
#pragma unroll
    for (int kc = 0; kc < 2; kc++) {
      short8 af[4], bfr[2];
#pragma unroll
      for (int mt = 0; mt < 4; mt++) {
        const int row = wy * 64 + mt * 16 + col;
        af[mt] = *(const short8*)&bA[row * 64 + (((kc * 4 + quad) ^ (row & 7)) << 3)];
      }
#pragma unroll
      for (int nt = 0; nt < 2; nt++) {
        const int row = wx * 32 + nt * 16 + col;
        bfr[nt] = *(const short8*)&bB[row * 64 + (((kc * 4 + quad) ^ (row & 7)) << 3)];
      }
#pragma unroll
      for (int mt = 0; mt < 4; mt++)
#pragma unroll
        for (int nt = 0; nt < 2; nt++)
          acc[mt][nt] = __builtin_amdgcn_mfma_f32_16x16x32_bf16(af[mt], bfr[nt], acc[mt][nt], 0, 0, 0);
    }
    if (++buf >= 3) buf = 0;
  }
#undef GSTAGE

#pragma unroll
  for (int mt = 0; mt < 4; mt++) {
#pragma unroll
    for (int nt = 0; nt < 2; nt++) {
      const int n = bn + wx * 32 + nt * 16 + col;
      const int mrow0 = bm + wy * 64 + mt * 16 + quad * 4;
      float bs = bias ? bias[n] : 0.f;
      if (STORE == 1) {
        bf16* C = (bf16*)Cv + coff;
        ushort4 pk;
        pk.x = f2bu(acc[mt][nt][0] + bs); pk.y = f2bu(acc[mt][nt][1] + bs);
        pk.z = f2bu(acc[mt][nt][2] + bs); pk.w = f2bu(acc[mt][nt][3] + bs);
        *(ushort4*)(C + (size_t)n * 4096 + mrow0) = pk;
      } else if (STORE == 2) {
        float* O = (float*)Cv + coff;
#pragma unroll
        for (int r = 0; r < 4; r++) {
          size_t gi = (size_t)(mrow0 + r) * ldc + n;
          O[gi] = acc[mt][nt][r] + bs + xres[gi];
        }
      } else if (STORE == 3) {
        bf16* C = (bf16*)Cv;
        const int pr = (mrow0 >> 11) * 3 + 3;   // all 4 rows in same batch (128-blocks)
#pragma unroll
        for (int r = 0; r < 4; r++)
          C[(size_t)(mrow0 + pr + r) * ldc + n] = f2b(acc[mt][nt][r] + bs);
      } else {
        bf16* C = (bf16*)Cv + coff;
#pragma unroll
        for (int r = 0; r < 4; r++) {
          float v = acc[mt][nt][r] + bs;
          if (ACT == 1) v = v / (1.f + expf(-v));  // silu
          C[(size_t)(mrow0 + r) * ldc + n] = f2b(v);
        }
      }
    }
  }
}

// T1 bijective XCD swizzle (m204 form, r=0 case; requires nwg % 8 == 0).
__device__ __forceinline__ int xcd_work_id() {
  const int nx = gridDim.x, ny = gridDim.y;
  const int d = blockIdx.x + nx * (blockIdx.y + ny * blockIdx.z);
  const int q = (nx * ny * (int)gridDim.z) >> 3;
  return (d & 7) * q + (d >> 3);
}

// template variant (conv, fin). Work-id decomposition wy-FAST: the 16 consecutive ids an
// XCD executes together share bn (B column panel ~512KB L2-resident) and stream the much
// smaller A panels — conv's 8MB convT was being re-streamed 4x/XCD with wx-fast order.
template <int ACT, int STORE, int APAD>
__global__ void __launch_bounds__(256) k_mgemm(const bf16* __restrict__ A, int lda,
                                               const bf16* __restrict__ WT,
                                               const float* __restrict__ bias,
                                               void* __restrict__ Cv,
                                               const float* __restrict__ xres,
                                               int ldc, int K,
                                               int gA, int gW, int gC) {
  const int wk = xcd_work_id();
  const int nx = gridDim.x, ny = gridDim.y;
  const int wy = wk % ny, rest = wk / ny;
  const int wx = rest % nx, g = rest / nx;
  mgemm_body(A + (size_t)g * gA, lda, WT + (size_t)g * gW, bias, Cv, xres,
             ldc, K, ACT, STORE, APAD, (size_t)g * gC, wy * 128, wx * 64);
}

// batched variant: z-slice selects one of 3 jobs (uniform scalar branches)
__global__ void __launch_bounds__(256) k_mgemmB(const bf16* A0, const bf16* A1, const bf16* A2,
                                                const bf16* W0, const bf16* W1, const bf16* W2,
                                                const float* b0, const float* b1, const float* b2,
                                                void* C0, void* C1, void* C2,
                                                int lda, int ldc, int K, int zPer,
                                                int gA, int gW, int gC,
                                                int actm, int storem, int apadm) {
  const int wk = xcd_work_id();
  const int nx = gridDim.x, ny = gridDim.y;
  const int wy = wk % ny, rest = wk / ny;
  const int wx = rest % nx, z = rest / nx;
  const int sel = z / zPer, zz = z % zPer;
  const bf16* A = (sel == 0 ? A0 : sel == 1 ? A1 : A2) + (size_t)zz * gA;
  const bf16* W = (sel == 0 ? W0 : sel == 1 ? W1 : W2) + (size_t)zz * gW;
  const float* bias = sel == 0 ? b0 : sel == 1 ? b1 : b2;
  void* Cv = sel == 0 ? C0 : sel == 1 ? C1 : C2;
  mgemm_body(A, lda, W, bias, Cv, nullptr, ldc, K,
             (actm >> sel) & 1, (storem >> (4 * sel)) & 15, (apadm >> sel) & 1,
             (size_t)zz * gC, wy * 128, wx * 64);
}

// ---------------- gate GEMV ----------------
__global__ void __launch_bounds__(256) k_gates(const bf16* __restrict__ q, const bf16* __restrict__ kk,
                                               const float* __restrict__ wi, const float* __restrict__ wib,
                                               const float* __restrict__ wf, const float* __restrict__ wfb,
                                               float* __restrict__ it, float* __restrict__ ft) {
  int gid  = blockIdx.x * 4 + (threadIdx.x >> 6);
  int lane = threadIdx.x & 63;
  int which = gid >> 12;
  int m = gid & 4095;
  const bf16* row = (which ? kk : q) + (size_t)m * DIM2X;
  const float* w = which ? wf : wi;
  float s[8] = {0, 0, 0, 0, 0, 0, 0, 0};
  for (int d = lane; d < DIM2X; d += 64) {
    float xv = b2f(row[d]);
    const float4* wp = (const float4*)(w + d * 8);
    float4 w0 = wp[0], w1 = wp[1];
    s[0] += xv * w0.x; s[1] += xv * w0.y; s[2] += xv * w0.z; s[3] += xv * w0.w;
    s[4] += xv * w1.x; s[5] += xv * w1.y; s[6] += xv * w1.z; s[7] += xv * w1.w;
  }
#pragma unroll
  for (int off = 32; off; off >>= 1) {
#pragma unroll
    for (int h = 0; h < 8; h++) s[h] += __shfl_xor(s[h], off);
  }
  if (lane == 0) {
    int b_ = m >> 11, tt = m & 2047;
    const float* wb = which ? wfb : wib;
    float* dst = which ? ft : it;
#pragma unroll
    for (int h = 0; h < 8; h++)
      dst[((size_t)(b_ * NHEADS + h)) * SEQ + tt] = s[h] + wb[h];
  }
}

// ---------------- per-(b,h) scan ----------------
__global__ void __launch_bounds__(256) k_scan(const float* __restrict__ it, const float* __restrict__ ft,
                                              float* __restrict__ cs, float* __restrict__ md) {
  const int bh = blockIdx.x;
  const int t  = threadIdx.x;
  const float* fr = ft + (size_t)bh * SEQ;
  const float* ir = it + (size_t)bh * SEQ;
  float* csr = cs + (size_t)bh * SEQ;
  float* mdr = md + (size_t)bh * SEQ;
  __shared__ float tmp[256];
  float loc[8]; float run = 0.f;
#pragma unroll
  for (int j = 0; j < 8; j++) {
    float xv = fr[t * 8 + j];
    float ls = fminf(xv, 0.f) - log1pf(expf(-fabsf(xv)));
    run += ls; loc[j] = run;
  }
  tmp[t] = run;
  __syncthreads();
  for (int off = 1; off < 256; off <<= 1) {
    float add = (t >= off) ? tmp[t - off] : 0.f;
    __syncthreads();
    tmp[t] += add;
    __syncthreads();
  }
  float exc = (t == 0) ? 0.f : tmp[t - 1];
  float csv[8];
#pragma unroll
  for (int j = 0; j < 8; j++) { csv[j] = loc[j] + exc; csr[t * 8 + j] = csv[j]; }
  __syncthreads();
  float rmax = -INFINITY; float gm[8];
#pragma unroll
  for (int j = 0; j < 8; j++) {
    float gv = ir[t * 8 + j] - csv[j];
    rmax = fmaxf(rmax, gv); gm[j] = rmax;
  }
  tmp[t] = rmax;
  __syncthreads();
  for (int off = 1; off < 256; off <<= 1) {
    float other = (t >= off) ? tmp[t - off] : -INFINITY;
    __syncthreads();
    tmp[t] = fmaxf(tmp[t], other);
    __syncthreads();
  }
  float emax = (t == 0) ? -INFINITY : tmp[t - 1];
#pragma unroll
  for (int j = 0; j < 8; j++) mdr[t * 8 + j] = csv[j] + fmaxf(gm[j], emax);
}

// ---------------- MFMA causal attention: 3-buffer pipeline + T5 setprio ----------------
// Single tile per block, grid (32,16). Stage-after-barrier 3-buffer pipeline, counted
// vmcnt(4/0). T5: s_setprio(1) around the MFMA clusters — multiple non-lockstep blocks
// per CU give the scheduler role diversity to arbitrate (m191: +4-7% on attn).
// FUSED GroupNorm + skip/bgate epilogue writes PRE directly.
__global__ void __launch_bounds__(256) k_attn_mfma(const bf16* __restrict__ qh,
                                                   const bf16* __restrict__ kh,
                                                   const bf16* __restrict__ vt,
                                                   const float* __restrict__ cs,
                                                   const float* __restrict__ md,
                                                   const float* __restrict__ itl,
                                                   const bf16* __restrict__ qk,
                                                   const bf16* __restrict__ bg,
                                                   const float* __restrict__ gw,
                                                   const float* __restrict__ gb,
                                                   const float* __restrict__ skip,
                                                   bf16* __restrict__ pre) {
  const int bh = blockIdx.y, b_ = bh >> 3, h = bh & 7;
  const int bx = blockIdx.x;
  const int tile = ((blockIdx.y >> 3) & 1) ? bx : 31 - bx;   // balanced pairing heuristic
  const int i0 = tile * 64;
  const int tid = threadIdx.x;
  const int w = tid >> 6;                     // wave 0..3 -> i-rows i0+16w..
  const int lane = tid & 63;
  const int col = lane & 15, quad = lane >> 4;
  const int i0w = i0 + w * 16;
  const int iwmax = i0w + 15;
  const float L2E = 1.44269504f;

  __shared__ __align__(16) bf16 smK[3 * 4096]; // [buf][j 32][d 128], chunk^(j&7) swizzle
  __shared__ __align__(16) bf16 smV[3 * 4096]; // [buf][n 128][j 32], chunk^((n>>1)&3) swizzle
  __shared__ __align__(16) bf16 Sc[4][16][40];

  const size_t baseQK = ((size_t)b_ * SEQ) * DIM2X + (size_t)h * HDIM;
  const size_t vtb = (size_t)(h * HDIM) * 4096 + (size_t)b_ * SEQ;
  const float* csp = cs + (size_t)bh * SEQ;
  const float* mdp = md + (size_t)bh * SEQ;
  const float* itp = itl + (size_t)bh * SEQ;

  short8 qf[4];
#pragma unroll
  for (int kc = 0; kc < 4; kc++)
    qf[kc] = *(const short8*)(qh + baseQK + (size_t)(i0w + col) * DIM2X + kc * 32 + quad * 8);

  float cs_i[4], md_i[4];                     // log2 domain
#pragma unroll
  for (int r = 0; r < 4; r++) {
    int i = i0w + quad * 4 + r;
    cs_i[r] = csp[i] * L2E; md_i[r] = mdp[i] * L2E;
  }

  f32x4 accpv[8];
#pragma unroll
  for (int nb = 0; nb < 8; nb++) accpv[nb] = (f32x4){0.f, 0.f, 0.f, 0.f};
  float rs[4] = {0.f, 0.f, 0.f, 0.f};

  // staging sources (thread t covers LDS chunk t of each 8KB buffer; source pre-swizzled)
  const int kj = tid >> 4, kq = tid & 15;     // K: row kj (+16), chunk kq
  const bf16* gKs = kh + baseQK + (size_t)kj * DIM2X + ((kq ^ (kj & 7)) * 8);
  const int vn = tid >> 2, vq = tid & 3;      // V: row vn (+64), chunk vq
  const bf16* gVs = vt + vtb + (size_t)vn * 4096 + ((vq ^ ((vn >> 1) & 3)) * 8);

  const int trips = 2 * tile + 2;

#define STAGE(buf, j0s)                                                        \
  do {                                                                         \
    bf16* dK = &smK[(buf) * 4096 + tid * 8];                                   \
    gl16(gKs + (size_t)(j0s) * DIM2X, dK);                                     \
    gl16(gKs + (size_t)((j0s) + 16) * DIM2X, dK + 2048);                       \
    bf16* dV = &smV[(buf) * 4096 + tid * 8];                                   \
    gl16(gVs + (j0s), dV);                                                     \
    gl16(gVs + (j0s) + (size_t)64 * 4096, dV + 2048);                          \
  } while (0)

  STAGE(0, 0);
  STAGE(1, 32);                               // trips >= 2 always
  int cur = 0;
  for (int t = 0; t < trips; ++t) {
    const int j0p = t * 32;
    if (t + 1 < trips) asm volatile("s_waitcnt vmcnt(4)" ::: "memory");
    else               asm volatile("s_waitcnt vmcnt(0)" ::: "memory");
    __builtin_amdgcn_s_barrier();
    if (t + 2 < trips) {
      int nb = cur + 2; if (nb >= 3) nb -= 3;
      STAGE(nb, j0p + 64);
    }
    asm volatile("" ::: "memory");
    if (j0p <= iwmax) {
      // hoisted gate loads, log2 domain
      float g0 = (itp[j0p + col] - csp[j0p + col]) * L2E;
      float g1 = (itp[j0p + 16 + col] - csp[j0p + 16 + col]) * L2E;
      const bool jt1 = (j0p + 16 <= iwmax);
#pragma unroll
      for (int jt = 0; jt < 2; jt++) {
        const int j0 = j0p + jt * 16;
        float sv[4] = {0.f, 0.f, 0.f, 0.f};
        if (jt == 0 || jt1) {
          const int jj = jt * 16 + col;
          f32x4 aq = (f32x4){0.f, 0.f, 0.f, 0.f};
          __builtin_amdgcn_s_setprio(1);
#pragma unroll
          for (int kc = 0; kc < 4; kc++) {
            short8 bk = *(const short8*)&smK[cur * 4096 + jj * 128 + ((((kc << 2) | quad) ^ (jj & 7)) << 3)];
            aq = __builtin_amdgcn_mfma_f32_16x16x32_bf16(qf[kc], bk, aq, 0, 0, 0);
          }
          __builtin_amdgcn_s_setprio(0);
          const int j = j0 + col;
          const float gj = jt ? g1 : g0;
#pragma unroll
          for (int r = 0; r < 4; r++) {
            const int i = i0w + quad * 4 + r;
            // arg <= -5 by construction (md = exact row max); 2^-5 = 1/tau
            float s = (j <= i) ? exp2f(cs_i[r] + gj - md_i[r] - 5.f) * aq[r] : 0.f;
            sv[r] = s; rs[r] += s;
          }
        }
#pragma unroll
        for (int r = 0; r < 4; r++) Sc[w][quad * 4 + r][jt * 16 + col] = f2b(sv[r]);
      }
      // own-wave cross-lane LDS round-trip: force write completion before read (rule #18)
      asm volatile("s_waitcnt lgkmcnt(0)" ::: "memory");
      __builtin_amdgcn_sched_barrier(0);
      short8 af = *(const short8*)(&Sc[w][col][quad * 8]);
      __builtin_amdgcn_s_setprio(1);
#pragma unroll
      for (int nb = 0; nb < 8; nb++) {
        const int rn = nb * 16 + col;
        short8 bv = *(const short8*)&smV[cur * 4096 + rn * 32 + ((quad ^ ((rn >> 1) & 3)) << 3)];
        accpv[nb] = __builtin_amdgcn_mfma_f32_16x16x32_bf16(af, bv, accpv[nb], 0, 0, 0);
      }
      __builtin_amdgcn_s_setprio(0);
    }
    cur = (cur + 1 == 3) ? 0 : cur + 1;
  }
#undef STAGE

  // ---- fused epilogue: H normalize + GroupNorm + skip/bgate, write PRE ----
#pragma unroll
  for (int r = 0; r < 4; r++) {
    float v = rs[r];
    v += __shfl_xor(v, 1); v += __shfl_xor(v, 2);
    v += __shfl_xor(v, 4); v += __shfl_xor(v, 8);
    rs[r] = v;
  }
  float inv[4];
#pragma unroll
  for (int r = 0; r < 4; r++) {
    float maxit = fmaxf(fabsf(rs[r]), exp2f(fminf(-md_i[r], 43.f)));
    inv[r] = 1.f / (maxit + 1e-8f);
  }
  // per-col params (col = h*128 + nb*16 + colIdx; independent of r)
  float gwv[8], gbv[8], skv[8];
#pragma unroll
  for (int nb = 0; nb < 8; nb++) {
    int c = h * HDIM + nb * 16 + col;
    gwv[nb] = gw[c]; gbv[nb] = gb[c]; skv[nb] = skip[c];
  }
#pragma unroll
  for (int r = 0; r < 4; r++) {
    const int row = i0w + quad * 4 + r;       // row within batch
    float s1 = 0.f, s2 = 0.f;
#pragma unroll
    for (int nb = 0; nb < 8; nb++) {
      float v = accpv[nb][r] * inv[r];
      s1 += v; s2 += v * v;
    }
    // reduce over the 16 lanes of this quad-group (all 128 head-dims of this row)
    s1 += __shfl_xor(s1, 1); s2 += __shfl_xor(s2, 1);
    s1 += __shfl_xor(s1, 2); s2 += __shfl_xor(s2, 2);
    s1 += __shfl_xor(s1, 4); s2 += __shfl_xor(s2, 4);
    s1 += __shfl_xor(s1, 8); s2 += __shfl_xor(s2, 8);
    float mu  = s1 * (1.f / 128.f);
    float var = s2 * (1.f / 128.f) - mu * mu;
    float rsg = rsqrtf(var + EPSF);
    const size_t rbase = baseQK + (size_t)row * DIM2X;   // includes batch+head offset
#pragma unroll
    for (int nb = 0; nb < 8; nb++) {
      float hv = accpv[nb][r] * inv[r];
      float hn = (hv - mu) * rsg * gwv[nb] + gbv[nb];
      size_t gi = rbase + nb * 16 + col;
      pre[gi] = f2b((hn + skv[nb] * b2f(qk[gi])) * b2f(bg[gi]));
    }
  }
}

extern "C" void kernel_launch(void* const* d_in, const int* in_sizes, int n_in,
                              void* d_out, int out_size, void* d_ws, size_t ws_size,
                              hipStream_t stream) {
  const float* x     = (const float*)d_in[0];
  const float* ln_w  = (const float*)d_in[1];
  const float* ln_b  = (const float*)d_in[2];
  const float* mlp1w = (const float*)d_in[3];
  const float* mlp1b = (const float*)d_in[4];
  const float* mlp2w = (const float*)d_in[5];
  const float* mlp2b = (const float*)d_in[6];
  const float* convw = (const float*)d_in[7];
  const float* convb = (const float*)d_in[8];
  const float* bqw   = (const float*)d_in[9];
  const float* bkw   = (const float*)d_in[10];
  const float* bvw   = (const float*)d_in[11];
  const float* wqw   = (const float*)d_in[12];
  const float* wqb   = (const float*)d_in[13];
  const float* wkw   = (const float*)d_in[14];
  const float* wkb   = (const float*)d_in[15];
  const float* wvw   = (const float*)d_in[16];
  const float* wvb   = (const float*)d_in[17];
  const float* wiw   = (const float*)d_in[18];
  const float* wib   = (const float*)d_in[19];
  const float* wfw   = (const float*)d_in[20];
  const float* wfb   = (const float*)d_in[21];
  const float* gnw   = (const float*)d_in[22];
  const float* gnb   = (const float*)d_in[23];
  const float* skip  = (const float*)d_in[24];
  const float* finw  = (const float*)d_in[25];
  const float* finb  = (const float*)d_in[26];
  float* out = (float*)d_out;

  float* GA  = (float*)d_ws;
  float* ITb = GA;
  float* FTb = GA + 32768;
  float* CSb = GA + 65536;
  float* MDb = GA + 98304;
  const size_t SLOT = 4u * 1024u * 1024u;
  bf16* S0 = (bf16*)((char*)d_ws + (1 << 20));
  bf16* S1 = S0 + SLOT;
  bf16* S2 = S1 + SLOT;
  bf16* S3 = S2 + SLOT;
  bf16* S4 = S3 + SLOT;
  bf16* S5 = S4 + SLOT;
  bf16* S6 = S5 + SLOT;
  bf16 *LN = S0, *BG = S2, *QKb = S3, *Qb = S4, *Kb = S5, *Vb = S6;
  bf16 *QH = S0, *KH = S1, *VT = S4, *PRE = S6;
  bf16* WTb   = S6 + SLOT;
  bf16* mlp1T = WTb;
  bf16* mlp2T = WTb + 524288;
  bf16* convT = WTb + 1048576;                 // [1024][4096] flat-K layout
  bf16* bqT   = WTb + 5242880;
  bf16* bkT   = bqT + 262144;
  bf16* bvT   = bkT + 262144;
  bf16* wqT   = bvT + 262144;
  bf16* wkT   = wqT + 1048576;
  bf16* wvT   = wkT + 1048576;
  bf16* finT  = wvT + 1048576;
  bf16* APD   = finT + 524288;                 // padded A: [2][2051][1024]

  // fused weight prep
  k_castT3<<<dim3(32, 16, 2), 256, 0, stream>>>(mlp1w, mlp2w, mlp2w, mlp1T, DIMX, DIM2X, 1, 0, 524288);
  k_castT3<<<dim3(32, 32, 3), 256, 0, stream>>>(wqw, wkw, wvw, wqT, DIM2X, DIM2X, 1, 0, 1048576);
  k_castT3<<<dim3(8, 8, 12), 256, 0, stream>>>(bqw, bkw, bvw, bqT, 256, 256, 4, 65536, 65536);
  k_castT3<<<dim3(16, 32, 1), 256, 0, stream>>>(finw, finw, finw, finT, DIM2X, DIMX, 1, 0, 524288);
  k_convwT<<<4096, 256, 0, stream>>>(convw, convT);
  k_zeropad<<<24, 256, 0, stream>>>(APD);

  k_layernorm<<<1024, 256, 0, stream>>>(x, ln_w, ln_b, LN);
  // batched mlp: sel0 = mlp1 -> APD (store3), sel1 = mlp2 -> BG (store0, silu)
  k_mgemmB<<<dim3(16, 32, 2), 256, 0, stream>>>(LN, LN, LN, mlp1T, mlp2T, mlp2T,
                                                mlp1b, mlp2b, mlp2b, APD, BG, BG,
                                                DIMX, DIM2X, DIMX, 1, 0, 0, 0,
                                                /*actm*/ 0b10, /*storem*/ 3 | (0 << 4), /*apadm*/ 0);
  // causal conv1d == single GEMM: K=4096 contiguous window over padded rows t..t+3
  k_mgemm<1, 0, 0><<<dim3(16, 16, 2), 256, 0, stream>>>(APD, DIM2X, convT, convb, QKb, nullptr,
                                                        DIM2X, 4096, PADROWS * DIM2X, 0, SEQ * DIM2X);
  // batched block-diag q/k/v: 12 z-slices (3 weights x 4 groups)
  k_mgemmB<<<dim3(4, 32, 12), 256, 0, stream>>>(QKb, QKb, APD, bqT, bkT, bvT,
                                                nullptr, nullptr, nullptr, Qb, Kb, Vb,
                                                DIM2X, DIM2X, 256, 4, 256, 65536, 256,
                                                /*actm*/ 0, /*storem*/ 0, /*apadm*/ 0b100);
  k_gates<<<2048, 256, 0, stream>>>(Qb, Kb, wiw, wib, wfw, wfb, ITb, FTb);
  k_scan<<<16, 256, 0, stream>>>(ITb, FTb, CSb, MDb);
  // batched wq/wk/wv: sel2 writes V^T (store1)
  k_mgemmB<<<dim3(16, 32, 3), 256, 0, stream>>>(Qb, Kb, Vb, wqT, wkT, wvT,
                                                wqb, wkb, wvb, QH, KH, VT,
                                                DIM2X, DIM2X, DIM2X, 1, 0, 0, 0,
                                                /*actm*/ 0, /*storem*/ 0 | (0 << 4) | (1 << 8), /*apadm*/ 0);
  // attention with fused GroupNorm + skip/bgate epilogue (writes PRE directly)
  k_attn_mfma<<<dim3(32, 16), 256, 0, stream>>>(QH, KH, VT, CSb, MDb, ITb,
                                                QKb, BG, gnw, gnb, skip, PRE);
  k_mgemm<0, 2, 0><<<dim3(8, 32), 256, 0, stream>>>(PRE, DIM2X, finT, finb, out, x, DIMX, DIM2X, 0, 0, 0);
}

// Round 15
// 434.353 us; speedup vs baseline: 1.0212x; 1.0212x over previous
//
#include <hip/hip_runtime.h>
#include <hip/hip_bf16.h>
#include <cmath>

typedef __hip_bfloat16 bf16;
typedef __attribute__((ext_vector_type(8))) short short8;   // 8 bf16 (4 VGPRs)
typedef __attribute__((ext_vector_type(4))) float f32x4;

#define SEQ   2048
#define DIMX  512
#define DIM2X 1024
#define NHEADS 8
#define HDIM  128
#define EPSF  1e-5f
#define PADROWS 2051   // 3 zero rows + 2048 per batch

__device__ __forceinline__ float b2f(bf16 v) { return __bfloat162float(v); }
__device__ __forceinline__ bf16 f2b(float f) { return __float2bfloat16(f); }
__device__ __forceinline__ unsigned short f2bu(float f) { bf16 t = __float2bfloat16(f); return *(unsigned short*)&t; }

// async global->LDS, 16B per lane. LDS dest must be linear in lane order (wave base + lane*16).
__device__ __forceinline__ void gl16(const bf16* g, bf16* l) {
  __builtin_amdgcn_global_load_lds((const __attribute__((address_space(1))) void*)g,
                                   (__attribute__((address_space(3))) void*)l, 16, 0, 0);
}

// ---------------- LayerNorm: one wave per row of 512 (fp32 in, bf16 out) ----------------
__global__ void __launch_bounds__(256) k_layernorm(const float* __restrict__ x,
                                                   const float* __restrict__ w,
                                                   const float* __restrict__ b,
                                                   bf16* __restrict__ out) {
  int row  = blockIdx.x * 4 + (threadIdx.x >> 6);
  int lane = threadIdx.x & 63;
  const float* xr = x + (size_t)row * DIMX;
  float v[8]; float s = 0.f, sq = 0.f;
#pragma unroll
  for (int i = 0; i < 8; i++) {
    float f = xr[lane + i * 64];
    v[i] = f; s += f; sq += f * f;
  }
#pragma unroll
  for (int off = 32; off; off >>= 1) { s += __shfl_xor(s, off); sq += __shfl_xor(sq, off); }
  float mu  = s * (1.f / DIMX);
  float var = sq * (1.f / DIMX) - mu * mu;
  float rs  = rsqrtf(var + EPSF);
  bf16* o = out + (size_t)row * DIMX;
#pragma unroll
  for (int i = 0; i < 8; i++) {
    int c = lane + i * 64;
    o[c] = f2b((v[i] - mu) * rs * w[c] + b[c]);
  }
}

// ---------------- fused weight cast+transpose: dst = sel-th of {W0,W1,W2} ----------------
__global__ void __launch_bounds__(256) k_castT3(const float* __restrict__ W0,
                                                const float* __restrict__ W1,
                                                const float* __restrict__ W2,
                                                bf16* __restrict__ WT,
                                                int K, int N, int innerZ, int gW, int gT) {
  __shared__ float t[32][33];
  const int z = blockIdx.z;
  const int sel = z / innerZ, zz = z % innerZ;
  const float* W = (sel == 0 ? W0 : sel == 1 ? W1 : W2) + (size_t)zz * gW;
  bf16* T = WT + (size_t)(sel * innerZ + zz) * gT;
  const int k0 = blockIdx.y * 32, n0 = blockIdx.x * 32;
  const int r = threadIdx.x >> 5, c = threadIdx.x & 31;
#pragma unroll
  for (int i = 0; i < 4; i++)
    t[r + i * 8][c] = W[(size_t)(k0 + r + i * 8) * N + n0 + c];
  __syncthreads();
#pragma unroll
  for (int i = 0; i < 4; i++)
    T[(size_t)(n0 + r + i * 8) * K + k0 + c] = f2b(t[c][r + i * 8]);
}

// ---------------- conv weight reshape (coalesced): thread = one (o,i) ----------------
__global__ void __launch_bounds__(256) k_convwT(const float* __restrict__ cw, bf16* __restrict__ wc) {
  int idx = blockIdx.x * 256 + threadIdx.x;     // (o,i)
  int o = idx >> 10, i = idx & 1023;
  float4 v = *(const float4*)(cw + (size_t)idx * 4);
  size_t base = (size_t)o * 4096 + i;
  wc[base]        = f2b(v.x);
  wc[base + 1024] = f2b(v.y);
  wc[base + 2048] = f2b(v.z);
  wc[base + 3072] = f2b(v.w);
}

// ---------------- zero the 3 pad rows before each batch of padded A ----------------
__global__ void __launch_bounds__(256) k_zeropad(bf16* __restrict__ p) {
  int idx = blockIdx.x * 256 + threadIdx.x;     // 6144 total
  int b = idx / 3072, off = idx % 3072;
  p[(size_t)b * PADROWS * DIM2X + off] = f2b(0.f);
}

// ---------------- GEMM body: 128x64 block, 4 waves, BK=64, 3-buffer counted pipeline ----------------
__device__ __forceinline__ void mgemm_body(const bf16* A, int lda, const bf16* WT,
                                           const float* bias, void* Cv, const float* xres,
                                           int ldc, int K, int ACT, int STORE, int APAD,
                                           size_t coff, int bm, int bn) {
  __shared__ __align__(16) bf16 smA[3][128 * 64];
  __shared__ __align__(16) bf16 smB[3][64 * 64];
  const int tid  = threadIdx.x;
  const int lane = tid & 63;
  const int w = tid >> 6, wy = w >> 1, wx = w & 1;
  const int col = lane & 15, quad = lane >> 4;

  const int r8 = tid >> 3, c8i = tid & 7;
  const int swz = (c8i ^ (r8 & 7)) * 8;       // (r8+p*32)&7 == r8&7
  const bf16* gA[4];
#pragma unroll
  for (int p = 0; p < 4; p++) {
    int ra = bm + r8 + p * 32;
    if (APAD) ra += (ra >> 11) * 3 + 3;
    gA[p] = A + (size_t)ra * lda + swz;
  }
  const bf16* gB[2];
#pragma unroll
  for (int p = 0; p < 2; p++)
    gB[p] = WT + (size_t)(bn + r8 + p * 32) * K + swz;

  f32x4 acc[4][2];
#pragma unroll
  for (int a = 0; a < 4; a++)
#pragma unroll
    for (int b = 0; b < 2; b++) acc[a][b] = (f32x4){0.f, 0.f, 0.f, 0.f};

  const int nsteps = K >> 6;                  // all K here are multiples of 64, nsteps >= 4

#define GSTAGE(buf, k0s)                                                       \
  do {                                                                         \
    bf16* dA = &smA[buf][tid * 8];                                             \
    gl16(gA[0] + (k0s), dA);                                                   \
    gl16(gA[1] + (k0s), dA + 2048);                                            \
    gl16(gA[2] + (k0s), dA + 4096);                                            \
    gl16(gA[3] + (k0s), dA + 6144);                                            \
    bf16* dB = &smB[buf][tid * 8];                                             \
    gl16(gB[0] + (k0s), dB);                                                   \
    gl16(gB[1] + (k0s), dB + 2048);                                            \
  } while (0)

  GSTAGE(0, 0);
  GSTAGE(1, 64);
  int buf = 0;
  for (int s = 0; s < nsteps; ++s) {
    if (s + 1 < nsteps) asm volatile("s_waitcnt vmcnt(6)" ::: "memory");
    else                asm volatile("s_waitcnt vmcnt(0)" ::: "memory");
    __builtin_amdgcn_s_barrier();
    if (s + 2 < nsteps) {
      int nb = buf + 2; if (nb >= 3) nb -= 3;
      GSTAGE(nb, (s + 2) * 64);
    }
    asm volatile("" ::: "memory");
    const bf16* bA = smA[buf];
    const bf16* bB = smB[buf];
#pragma unroll
    for (int kc = 0; kc < 2; kc++) {
      short8 af[4], bfr[2];
#pragma unroll
      for (int mt = 0; mt < 4; mt++) {
        const int row = wy * 64 + mt * 16 + col;
        af[mt] = *(const short8*)&bA[row * 64 + (((kc * 4 + quad) ^ (row & 7)) << 3)];
      }
#pragma unroll
      for (int nt = 0; nt < 2; nt++) {
        const int row = wx * 32 + nt * 16 + col;
        bfr[nt] = *(const short8*)&bB[row * 64 + (((kc * 4 + quad) ^ (row & 7)) << 3)];
      }
#pragma unroll
      for (int mt = 0; mt < 4; mt++)
#pragma unroll
        for (int nt = 0; nt < 2; nt++)
          acc[mt][nt] = __builtin_amdgcn_mfma_f32_16x16x32_bf16(af[mt], bfr[nt], acc[mt][nt], 0, 0, 0);
    }
    if (++buf >= 3) buf = 0;
  }
#undef GSTAGE

#pragma unroll
  for (int mt = 0; mt < 4; mt++) {
#pragma unroll
    for (int nt = 0; nt < 2; nt++) {
      const int n = bn + wx * 32 + nt * 16 + col;
      const int mrow0 = bm + wy * 64 + mt * 16 + quad * 4;
      float bs = bias ? bias[n] : 0.f;
      if (STORE == 1) {
        bf16* C = (bf16*)Cv + coff;
        ushort4 pk;
        pk.x = f2bu(acc[mt][nt][0] + bs); pk.y = f2bu(acc[mt][nt][1] + bs);
        pk.z = f2bu(acc[mt][nt][2] + bs); pk.w = f2bu(acc[mt][nt][3] + bs);
        *(ushort4*)(C + (size_t)n * 4096 + mrow0) = pk;
      } else if (STORE == 2) {
        float* O = (float*)Cv + coff;
#pragma unroll
        for (int r = 0; r < 4; r++) {
          size_t gi = (size_t)(mrow0 + r) * ldc + n;
          O[gi] = acc[mt][nt][r] + bs + xres[gi];
        }
      } else if (STORE == 3) {
        bf16* C = (bf16*)Cv;
        const int pr = (mrow0 >> 11) * 3 + 3;   // all 4 rows in same batch (128-blocks)
#pragma unroll
        for (int r = 0; r < 4; r++)
          C[(size_t)(mrow0 + pr + r) * ldc + n] = f2b(acc[mt][nt][r] + bs);
      } else {
        bf16* C = (bf16*)Cv + coff;
#pragma unroll
        for (int r = 0; r < 4; r++) {
          float v = acc[mt][nt][r] + bs;
          if (ACT == 1) v = v / (1.f + expf(-v));  // silu
          C[(size_t)(mrow0 + r) * ldc + n] = f2b(v);
        }
      }
    }
  }
}

// T1 bijective XCD swizzle (m204 form, r=0 case; requires nwg % 8 == 0).
__device__ __forceinline__ int xcd_work_id() {
  const int nx = gridDim.x, ny = gridDim.y;
  const int d = blockIdx.x + nx * (blockIdx.y + ny * blockIdx.z);
  const int q = (nx * ny * (int)gridDim.z) >> 3;
  return (d & 7) * q + (d >> 3);
}

// template variant (conv, fin). wx-FAST work-id order (round-9/13 form — round-14's
// wy-fast A/B'd at -10us: it breaks A-panel L2 sharing among an XCD's consecutive ids).
template <int ACT, int STORE, int APAD>
__global__ void __launch_bounds__(256) k_mgemm(const bf16* __restrict__ A, int lda,
                                               const bf16* __restrict__ WT,
                                               const float* __restrict__ bias,
                                               void* __restrict__ Cv,
                                               const float* __restrict__ xres,
                                               int ldc, int K,
                                               int gA, int gW, int gC) {
  const int wk = xcd_work_id();
  const int nx = gridDim.x, ny = gridDim.y;
  const int wx = wk % nx, rest = wk / nx;
  const int wy = rest % ny, g = rest / ny;
  mgemm_body(A + (size_t)g * gA, lda, WT + (size_t)g * gW, bias, Cv, xres,
             ldc, K, ACT, STORE, APAD, (size_t)g * gC, wy * 128, wx * 64);
}

// batched variant: z-slice selects one of 3 jobs (uniform scalar branches)
__global__ void __launch_bounds__(256) k_mgemmB(const bf16* A0, const bf16* A1, const bf16* A2,
                                                const bf16* W0, const bf16* W1, const bf16* W2,
                                                const float* b0, const float* b1, const float* b2,
                                                void* C0, void* C1, void* C2,
                                                int lda, int ldc, int K, int zPer,
                                                int gA, int gW, int gC,
                                                int actm, int storem, int apadm) {
  const int wk = xcd_work_id();
  const int nx = gridDim.x, ny = gridDim.y;
  const int wx = wk % nx, rest = wk / nx;
  const int wy = rest % ny, z = rest / ny;
  const int sel = z / zPer, zz = z % zPer;
  const bf16* A = (sel == 0 ? A0 : sel == 1 ? A1 : A2) + (size_t)zz * gA;
  const bf16* W = (sel == 0 ? W0 : sel == 1 ? W1 : W2) + (size_t)zz * gW;
  const float* bias = sel == 0 ? b0 : sel == 1 ? b1 : b2;
  void* Cv = sel == 0 ? C0 : sel == 1 ? C1 : C2;
  mgemm_body(A, lda, W, bias, Cv, nullptr, ldc, K,
             (actm >> sel) & 1, (storem >> (4 * sel)) & 15, (apadm >> sel) & 1,
             (size_t)zz * gC, wy * 128, wx * 64);
}

// ---------------- gate GEMV ----------------
__global__ void __launch_bounds__(256) k_gates(const bf16* __restrict__ q, const bf16* __restrict__ kk,
                                               const float* __restrict__ wi, const float* __restrict__ wib,
                                               const float* __restrict__ wf, const float* __restrict__ wfb,
                                               float* __restrict__ it, float* __restrict__ ft) {
  int gid  = blockIdx.x * 4 + (threadIdx.x >> 6);
  int lane = threadIdx.x & 63;
  int which = gid >> 12;
  int m = gid & 4095;
  const bf16* row = (which ? kk : q) + (size_t)m * DIM2X;
  const float* w = which ? wf : wi;
  float s[8] = {0, 0, 0, 0, 0, 0, 0, 0};
  for (int d = lane; d < DIM2X; d += 64) {
    float xv = b2f(row[d]);
    const float4* wp = (const float4*)(w + d * 8);
    float4 w0 = wp[0], w1 = wp[1];
    s[0] += xv * w0.x; s[1] += xv * w0.y; s[2] += xv * w0.z; s[3] += xv * w0.w;
    s[4] += xv * w1.x; s[5] += xv * w1.y; s[6] += xv * w1.z; s[7] += xv * w1.w;
  }
#pragma unroll
  for (int off = 32; off; off >>= 1) {
#pragma unroll
    for (int h = 0; h < 8; h++) s[h] += __shfl_xor(s[h], off);
  }
  if (lane == 0) {
    int b_ = m >> 11, tt = m & 2047;
    const float* wb = which ? wfb : wib;
    float* dst = which ? ft : it;
#pragma unroll
    for (int h = 0; h < 8; h++)
      dst[((size_t)(b_ * NHEADS + h)) * SEQ + tt] = s[h] + wb[h];
  }
}

// ---------------- per-(b,h) scan ----------------
__global__ void __launch_bounds__(256) k_scan(const float* __restrict__ it, const float* __restrict__ ft,
                                              float* __restrict__ cs, float* __restrict__ md) {
  const int bh = blockIdx.x;
  const int t  = threadIdx.x;
  const float* fr = ft + (size_t)bh * SEQ;
  const float* ir = it + (size_t)bh * SEQ;
  float* csr = cs + (size_t)bh * SEQ;
  float* mdr = md + (size_t)bh * SEQ;
  __shared__ float tmp[256];
  float loc[8]; float run = 0.f;
#pragma unroll
  for (int j = 0; j < 8; j++) {
    float xv = fr[t * 8 + j];
    float ls = fminf(xv, 0.f) - log1pf(expf(-fabsf(xv)));
    run += ls; loc[j] = run;
  }
  tmp[t] = run;
  __syncthreads();
  for (int off = 1; off < 256; off <<= 1) {
    float add = (t >= off) ? tmp[t - off] : 0.f;
    __syncthreads();
    tmp[t] += add;
    __syncthreads();
  }
  float exc = (t == 0) ? 0.f : tmp[t - 1];
  float csv[8];
#pragma unroll
  for (int j = 0; j < 8; j++) { csv[j] = loc[j] + exc; csr[t * 8 + j] = csv[j]; }
  __syncthreads();
  float rmax = -INFINITY; float gm[8];
#pragma unroll
  for (int j = 0; j < 8; j++) {
    float gv = ir[t * 8 + j] - csv[j];
    rmax = fmaxf(rmax, gv); gm[j] = rmax;
  }
  tmp[t] = rmax;
  __syncthreads();
  for (int off = 1; off < 256; off <<= 1) {
    float other = (t >= off) ? tmp[t - off] : -INFINITY;
    __syncthreads();
    tmp[t] = fmaxf(tmp[t], other);
    __syncthreads();
  }
  float emax = (t == 0) ? -INFINITY : tmp[t - 1];
#pragma unroll
  for (int j = 0; j < 8; j++) mdr[t * 8 + j] = csv[j] + fmaxf(gm[j], emax);
}

// ---------------- MFMA causal attention: 3-buffer pipeline + T5 setprio ----------------
// Single tile per block, grid (32,16). Stage-after-barrier 3-buffer pipeline, counted
// vmcnt(4/0). T5 setprio around MFMA clusters (round 14: 110.6 -> 101.8us, +8%).
// FUSED GroupNorm + skip/bgate epilogue writes PRE directly.
__global__ void __launch_bounds__(256) k_attn_mfma(const bf16* __restrict__ qh,
                                                   const bf16* __restrict__ kh,
                                                   const bf16* __restrict__ vt,
                                                   const float* __restrict__ cs,
                                                   const float* __restrict__ md,
                                                   const float* __restrict__ itl,
                                                   const bf16* __restrict__ qk,
                                                   const bf16* __restrict__ bg,
                                                   const float* __restrict__ gw,
                                                   const float* __restrict__ gb,
                                                   const float* __restrict__ skip,
                                                   bf16* __restrict__ pre) {
  const int bh = blockIdx.y, b_ = bh >> 3, h = bh & 7;
  const int bx = blockIdx.x;
  const int tile = ((blockIdx.y >> 3) & 1) ? bx : 31 - bx;   // balanced pairing heuristic
  const int i0 = tile * 64;
  const int tid = threadIdx.x;
  const int w = tid >> 6;                     // wave 0..3 -> i-rows i0+16w..
  const int lane = tid & 63;
  const int col = lane & 15, quad = lane >> 4;
  const int i0w = i0 + w * 16;
  const int iwmax = i0w + 15;
  const float L2E = 1.44269504f;

  __shared__ __align__(16) bf16 smK[3 * 4096]; // [buf][j 32][d 128], chunk^(j&7) swizzle
  __shared__ __align__(16) bf16 smV[3 * 4096]; // [buf][n 128][j 32], chunk^((n>>1)&3) swizzle
  __shared__ __align__(16) bf16 Sc[4][16][40];

  const size_t baseQK = ((size_t)b_ * SEQ) * DIM2X + (size_t)h * HDIM;
  const size_t vtb = (size_t)(h * HDIM) * 4096 + (size_t)b_ * SEQ;
  const float* csp = cs + (size_t)bh * SEQ;
  const float* mdp = md + (size_t)bh * SEQ;
  const float* itp = itl + (size_t)bh * SEQ;

  short8 qf[4];
#pragma unroll
  for (int kc = 0; kc < 4; kc++)
    qf[kc] = *(const short8*)(qh + baseQK + (size_t)(i0w + col) * DIM2X + kc * 32 + quad * 8);

  float cs_i[4], md_i[4];                     // log2 domain
#pragma unroll
  for (int r = 0; r < 4; r++) {
    int i = i0w + quad * 4 + r;
    cs_i[r] = csp[i] * L2E; md_i[r] = mdp[i] * L2E;
  }

  f32x4 accpv[8];
#pragma unroll
  for (int nb = 0; nb < 8; nb++) accpv[nb] = (f32x4){0.f, 0.f, 0.f, 0.f};
  float rs[4] = {0.f, 0.f, 0.f, 0.f};

  // staging sources (thread t covers LDS chunk t of each 8KB buffer; source pre-swizzled)
  const int kj = tid >> 4, kq = tid & 15;     // K: row kj (+16), chunk kq
  const bf16* gKs = kh + baseQK + (size_t)kj * DIM2X + ((kq ^ (kj & 7)) * 8);
  const int vn = tid >> 2, vq = tid & 3;      // V: row vn (+64), chunk vq
  const bf16* gVs = vt + vtb + (size_t)vn * 4096 + ((vq ^ ((vn >> 1) & 3)) * 8);

  const int trips = 2 * tile + 2;

#define STAGE(buf, j0s)                                                        \
  do {                                                                         \
    bf16* dK = &smK[(buf) * 4096 + tid * 8];                                   \
    gl16(gKs + (size_t)(j0s) * DIM2X, dK);                                     \
    gl16(gKs + (size_t)((j0s) + 16) * DIM2X, dK + 2048);                       \
    bf16* dV = &smV[(buf) * 4096 + tid * 8];                                   \
    gl16(gVs + (j0s), dV);                                                     \
    gl16(gVs + (j0s) + (size_t)64 * 4096, dV + 2048);                          \
  } while (0)

  STAGE(0, 0);
  STAGE(1, 32);                               // trips >= 2 always
  int cur = 0;
  for (int t = 0; t < trips; ++t) {
    const int j0p = t * 32;
    if (t + 1 < trips) asm volatile("s_waitcnt vmcnt(4)" ::: "memory");
    else               asm volatile("s_waitcnt vmcnt(0)" ::: "memory");
    __builtin_amdgcn_s_barrier();
    if (t + 2 < trips) {
      int nb = cur + 2; if (nb >= 3) nb -= 3;
      STAGE(nb, j0p + 64);
    }
    asm volatile("" ::: "memory");
    if (j0p <= iwmax) {
      // hoisted gate loads, log2 domain
      float g0 = (itp[j0p + col] - csp[j0p + col]) * L2E;
      float g1 = (itp[j0p + 16 + col] - csp[j0p + 16 + col]) * L2E;
      const bool jt1 = (j0p + 16 <= iwmax);
#pragma unroll
      for (int jt = 0; jt < 2; jt++) {
        const int j0 = j0p + jt * 16;
        float sv[4] = {0.f, 0.f, 0.f, 0.f};
        if (jt == 0 || jt1) {
          const int jj = jt * 16 + col;
          f32x4 aq = (f32x4){0.f, 0.f, 0.f, 0.f};
          __builtin_amdgcn_s_setprio(1);
#pragma unroll
          for (int kc = 0; kc < 4; kc++) {
            short8 bk = *(const short8*)&smK[cur * 4096 + jj * 128 + ((((kc << 2) | quad) ^ (jj & 7)) << 3)];
            aq = __builtin_amdgcn_mfma_f32_16x16x32_bf16(qf[kc], bk, aq, 0, 0, 0);
          }
          __builtin_amdgcn_s_setprio(0);
          const int j = j0 + col;
          const float gj = jt ? g1 : g0;
#pragma unroll
          for (int r = 0; r < 4; r++) {
            const int i = i0w + quad * 4 + r;
            // arg <= -5 by construction (md = exact row max); 2^-5 = 1/tau
            float s = (j <= i) ? exp2f(cs_i[r] + gj - md_i[r] - 5.f) * aq[r] : 0.f;
            sv[r] = s; rs[r] += s;
          }
        }
#pragma unroll
        for (int r = 0; r < 4; r++) Sc[w][quad * 4 + r][jt * 16 + col] = f2b(sv[r]);
      }
      // own-wave cross-lane LDS round-trip: force write completion before read (rule #18)
      asm volatile("s_waitcnt lgkmcnt(0)" ::: "memory");
      __builtin_amdgcn_sched_barrier(0);
      short8 af = *(const short8*)(&Sc[w][col][quad * 8]);
      __builtin_amdgcn_s_setprio(1);
#pragma unroll
      for (int nb = 0; nb < 8; nb++) {
        const int rn = nb * 16 + col;
        short8 bv = *(const short8*)&smV[cur * 4096 + rn * 32 + ((quad ^ ((rn >> 1) & 3)) << 3)];
        accpv[nb] = __builtin_amdgcn_mfma_f32_16x16x32_bf16(af, bv, accpv[nb], 0, 0, 0);
      }
      __builtin_amdgcn_s_setprio(0);
    }
    cur = (cur + 1 == 3) ? 0 : cur + 1;
  }
#undef STAGE

  // ---- fused epilogue: H normalize + GroupNorm + skip/bgate, write PRE ----
#pragma unroll
  for (int r = 0; r < 4; r++) {
    float v = rs[r];
    v += __shfl_xor(v, 1); v += __shfl_xor(v, 2);
    v += __shfl_xor(v, 4); v += __shfl_xor(v, 8);
    rs[r] = v;
  }
  float inv[4];
#pragma unroll
  for (int r = 0; r < 4; r++) {
    float maxit = fmaxf(fabsf(rs[r]), exp2f(fminf(-md_i[r], 43.f)));
    inv[r] = 1.f / (maxit + 1e-8f);
  }
  // per-col params (col = h*128 + nb*16 + colIdx; independent of r)
  float gwv[8], gbv[8], skv[8];
#pragma unroll
  for (int nb = 0; nb < 8; nb++) {
    int c = h * HDIM + nb * 16 + col;
    gwv[nb] = gw[c]; gbv[nb] = gb[c]; skv[nb] = skip[c];
  }
#pragma unroll
  for (int r = 0; r < 4; r++) {
    const int row = i0w + quad * 4 + r;       // row within batch
    float s1 = 0.f, s2 = 0.f;
#pragma unroll
    for (int nb = 0; nb < 8; nb++) {
      float v = accpv[nb][r] * inv[r];
      s1 += v; s2 += v * v;
    }
    // reduce over the 16 lanes of this quad-group (all 128 head-dims of this row)
    s1 += __shfl_xor(s1, 1); s2 += __shfl_xor(s2, 1);
    s1 += __shfl_xor(s1, 2); s2 += __shfl_xor(s2, 2);
    s1 += __shfl_xor(s1, 4); s2 += __shfl_xor(s2, 4);
    s1 += __shfl_xor(s1, 8); s2 += __shfl_xor(s2, 8);
    float mu  = s1 * (1.f / 128.f);
    float var = s2 * (1.f / 128.f) - mu * mu;
    float rsg = rsqrtf(var + EPSF);
    const size_t rbase = baseQK + (size_t)row * DIM2X;   // includes batch+head offset
#pragma unroll
    for (int nb = 0; nb < 8; nb++) {
      float hv = accpv[nb][r] * inv[r];
      float hn = (hv - mu) * rsg * gwv[nb] + gbv[nb];
      size_t gi = rbase + nb * 16 + col;
      pre[gi] = f2b((hn + skv[nb] * b2f(qk[gi])) * b2f(bg[gi]));
    }
  }
}

extern "C" void kernel_launch(void* const* d_in, const int* in_sizes, int n_in,
                              void* d_out, int out_size, void* d_ws, size_t ws_size,
                              hipStream_t stream) {
  const float* x     = (const float*)d_in[0];
  const float* ln_w  = (const float*)d_in[1];
  const float* ln_b  = (const float*)d_in[2];
  const float* mlp1w = (const float*)d_in[3];
  const float* mlp1b = (const float*)d_in[4];
  const float* mlp2w = (const float*)d_in[5];
  const float* mlp2b = (const float*)d_in[6];
  const float* convw = (const float*)d_in[7];
  const float* convb = (const float*)d_in[8];
  const float* bqw   = (const float*)d_in[9];
  const float* bkw   = (const float*)d_in[10];
  const float* bvw   = (const float*)d_in[11];
  const float* wqw   = (const float*)d_in[12];
  const float* wqb   = (const float*)d_in[13];
  const float* wkw   = (const float*)d_in[14];
  const float* wkb   = (const float*)d_in[15];
  const float* wvw   = (const float*)d_in[16];
  const float* wvb   = (const float*)d_in[17];
  const float* wiw   = (const float*)d_in[18];
  const float* wib   = (const float*)d_in[19];
  const float* wfw   = (const float*)d_in[20];
  const float* wfb   = (const float*)d_in[21];
  const float* gnw   = (const float*)d_in[22];
  const float* gnb   = (const float*)d_in[23];
  const float* skip  = (const float*)d_in[24];
  const float* finw  = (const float*)d_in[25];
  const float* finb  = (const float*)d_in[26];
  float* out = (float*)d_out;

  float* GA  = (float*)d_ws;
  float* ITb = GA;
  float* FTb = GA + 32768;
  float* CSb = GA + 65536;
  float* MDb = GA + 98304;
  const size_t SLOT = 4u * 1024u * 1024u;
  bf16* S0 = (bf16*)((char*)d_ws + (1 << 20));
  bf16* S1 = S0 + SLOT;
  bf16* S2 = S1 + SLOT;
  bf16* S3 = S2 + SLOT;
  bf16* S4 = S3 + SLOT;
  bf16* S5 = S4 + SLOT;
  bf16* S6 = S5 + SLOT;
  bf16 *LN = S0, *BG = S2, *QKb = S3, *Qb = S4, *Kb = S5, *Vb = S6;
  bf16 *QH = S0, *KH = S1, *VT = S4, *PRE = S6;
  bf16* WTb   = S6 + SLOT;
  bf16* mlp1T = WTb;
  bf16* mlp2T = WTb + 524288;
  bf16* convT = WTb + 1048576;                 // [1024][4096] flat-K layout
  bf16* bqT   = WTb + 5242880;
  bf16* bkT   = bqT + 262144;
  bf16* bvT   = bkT + 262144;
  bf16* wqT   = bvT + 262144;
  bf16* wkT   = wqT + 1048576;
  bf16* wvT   = wkT + 1048576;
  bf16* finT  = wvT + 1048576;
  bf16* APD   = finT + 524288;                 // padded A: [2][2051][1024]

  // fused weight prep
  k_castT3<<<dim3(32, 16, 2), 256, 0, stream>>>(mlp1w, mlp2w, mlp2w, mlp1T, DIMX, DIM2X, 1, 0, 524288);
  k_castT3<<<dim3(32, 32, 3), 256, 0, stream>>>(wqw, wkw, wvw, wqT, DIM2X, DIM2X, 1, 0, 1048576);
  k_castT3<<<dim3(8, 8, 12), 256, 0, stream>>>(bqw, bkw, bvw, bqT, 256, 256, 4, 65536, 65536);
  k_castT3<<<dim3(16, 32, 1), 256, 0, stream>>>(finw, finw, finw, finT, DIM2X, DIMX, 1, 0, 524288);
  k_convwT<<<4096, 256, 0, stream>>>(convw, convT);
  k_zeropad<<<24, 256, 0, stream>>>(APD);

  k_layernorm<<<1024, 256, 0, stream>>>(x, ln_w, ln_b, LN);
  // batched mlp: sel0 = mlp1 -> APD (store3), sel1 = mlp2 -> BG (store0, silu)
  k_mgemmB<<<dim3(16, 32, 2), 256, 0, stream>>>(LN, LN, LN, mlp1T, mlp2T, mlp2T,
                                                mlp1b, mlp2b, mlp2b, APD, BG, BG,
                                                DIMX, DIM2X, DIMX, 1, 0, 0, 0,
                                                /*actm*/ 0b10, /*storem*/ 3 | (0 << 4), /*apadm*/ 0);
  // causal conv1d == single GEMM: K=4096 contiguous window over padded rows t..t+3
  k_mgemm<1, 0, 0><<<dim3(16, 16, 2), 256, 0, stream>>>(APD, DIM2X, convT, convb, QKb, nullptr,
                                                        DIM2X, 4096, PADROWS * DIM2X, 0, SEQ * DIM2X);
  // batched block-diag q/k/v: 12 z-slices (3 weights x 4 groups)
  k_mgemmB<<<dim3(4, 32, 12), 256, 0, stream>>>(QKb, QKb, APD, bqT, bkT, bvT,
                                                nullptr, nullptr, nullptr, Qb, Kb, Vb,
                                                DIM2X, DIM2X, 256, 4, 256, 65536, 256,
                                                /*actm*/ 0, /*storem*/ 0, /*apadm*/ 0b100);
  k_gates<<<2048, 256, 0, stream>>>(Qb, Kb, wiw, wib, wfw, wfb, ITb, FTb);
  k_scan<<<16, 256, 0, stream>>>(ITb, FTb, CSb, MDb);
  // batched wq/wk/wv: sel2 writes V^T (store1)
  k_mgemmB<<<dim3(16, 32, 3), 256, 0, stream>>>(Qb, Kb, Vb, wqT, wkT, wvT,
                                                wqb, wkb, wvb, QH, KH, VT,
                                                DIM2X, DIM2X, DIM2X, 1, 0, 0, 0,
                                                /*actm*/ 0, /*storem*/ 0 | (0 << 4) | (1 << 8), /*apadm*/ 0);
  // attention with fused GroupNorm + skip/bgate epilogue (writes PRE directly)
  k_attn_mfma<<<dim3(32, 16), 256, 0, stream>>>(QH, KH, VT, CSb, MDb, ITb,
                                                QKb, BG, gnw, gnb, skip, PRE);
  k_mgemm<0, 2, 0><<<dim3(8, 32), 256, 0, stream>>>(PRE, DIM2X, finT, finb, out, x, DIMX, DIM2X, 0, 0, 0);
}

// Round 16
// 433.202 us; speedup vs baseline: 1.0240x; 1.0027x over previous
//
#include <hip/hip_runtime.h>
#include <hip/hip_bf16.h>
#include <cmath>

typedef __hip_bfloat16 bf16;
typedef __attribute__((ext_vector_type(8))) short short8;   // 8 bf16 (4 VGPRs)
typedef __attribute__((ext_vector_type(4))) float f32x4;

#define SEQ   2048
#define DIMX  512
#define DIM2X 1024
#define NHEADS 8
#define HDIM  128
#define EPSF  1e-5f
#define PADROWS 2051   // 3 zero rows + 2048 per batch

__device__ __forceinline__ float b2f(bf16 v) { return __bfloat162float(v); }
__device__ __forceinline__ bf16 f2b(float f) { return __float2bfloat16(f); }
__device__ __forceinline__ unsigned short f2bu(float f) { bf16 t = __float2bfloat16(f); return *(unsigned short*)&t; }

// async global->LDS, 16B per lane. LDS dest must be linear in lane order (wave base + lane*16).
__device__ __forceinline__ void gl16(const bf16* g, bf16* l) {
  __builtin_amdgcn_global_load_lds((const __attribute__((address_space(1))) void*)g,
                                   (__attribute__((address_space(3))) void*)l, 16, 0, 0);
}

// ---------------- LayerNorm: one wave per row of 512 (fp32 in, bf16 out) ----------------
__global__ void __launch_bounds__(256) k_layernorm(const float* __restrict__ x,
                                                   const float* __restrict__ w,
                                                   const float* __restrict__ b,
                                                   bf16* __restrict__ out) {
  int row  = blockIdx.x * 4 + (threadIdx.x >> 6);
  int lane = threadIdx.x & 63;
  const float* xr = x + (size_t)row * DIMX;
  float v[8]; float s = 0.f, sq = 0.f;
#pragma unroll
  for (int i = 0; i < 8; i++) {
    float f = xr[lane + i * 64];
    v[i] = f; s += f; sq += f * f;
  }
#pragma unroll
  for (int off = 32; off; off >>= 1) { s += __shfl_xor(s, off); sq += __shfl_xor(sq, off); }
  float mu  = s * (1.f / DIMX);
  float var = sq * (1.f / DIMX) - mu * mu;
  float rs  = rsqrtf(var + EPSF);
  bf16* o = out + (size_t)row * DIMX;
#pragma unroll
  for (int i = 0; i < 8; i++) {
    int c = lane + i * 64;
    o[c] = f2b((v[i] - mu) * rs * w[c] + b[c]);
  }
}

// ---------------- fused weight cast+transpose: dst = sel-th of {W0,W1,W2} ----------------
__global__ void __launch_bounds__(256) k_castT3(const float* __restrict__ W0,
                                                const float* __restrict__ W1,
                                                const float* __restrict__ W2,
                                                bf16* __restrict__ WT,
                                                int K, int N, int innerZ, int gW, int gT) {
  __shared__ float t[32][33];
  const int z = blockIdx.z;
  const int sel = z / innerZ, zz = z % innerZ;
  const float* W = (sel == 0 ? W0 : sel == 1 ? W1 : W2) + (size_t)zz * gW;
  bf16* T = WT + (size_t)(sel * innerZ + zz) * gT;
  const int k0 = blockIdx.y * 32, n0 = blockIdx.x * 32;
  const int r = threadIdx.x >> 5, c = threadIdx.x & 31;
#pragma unroll
  for (int i = 0; i < 4; i++)
    t[r + i * 8][c] = W[(size_t)(k0 + r + i * 8) * N + n0 + c];
  __syncthreads();
#pragma unroll
  for (int i = 0; i < 4; i++)
    T[(size_t)(n0 + r + i * 8) * K + k0 + c] = f2b(t[c][r + i * 8]);
}

// ---------------- conv weight reshape (coalesced): thread = one (o,i) ----------------
__global__ void __launch_bounds__(256) k_convwT(const float* __restrict__ cw, bf16* __restrict__ wc) {
  int idx = blockIdx.x * 256 + threadIdx.x;     // (o,i)
  int o = idx >> 10, i = idx & 1023;
  float4 v = *(const float4*)(cw + (size_t)idx * 4);
  size_t base = (size_t)o * 4096 + i;
  wc[base]        = f2b(v.x);
  wc[base + 1024] = f2b(v.y);
  wc[base + 2048] = f2b(v.z);
  wc[base + 3072] = f2b(v.w);
}

// ---------------- zero the 3 pad rows before each batch of padded A ----------------
__global__ void __launch_bounds__(256) k_zeropad(bf16* __restrict__ p) {
  int idx = blockIdx.x * 256 + threadIdx.x;     // 6144 total
  int b = idx / 3072, off = idx % 3072;
  p[(size_t)b * PADROWS * DIM2X + off] = f2b(0.f);
}

// ---------------- GEMM body: 128x64 block, 4 waves, BK=64, 3-buffer counted pipeline ----------------
// T5 setprio around the MFMA cluster (same mechanism as attn's round-14 +8%: multiple
// non-lockstep blocks/CU -> scheduler can prefer the MFMA-entering wave).
__device__ __forceinline__ void mgemm_body(const bf16* A, int lda, const bf16* WT,
                                           const float* bias, void* Cv, const float* xres,
                                           int ldc, int K, int ACT, int STORE, int APAD,
                                           size_t coff, int bm, int bn) {
  __shared__ __align__(16) bf16 smA[3][128 * 64];
  __shared__ __align__(16) bf16 smB[3][64 * 64];
  const int tid  = threadIdx.x;
  const int lane = tid & 63;
  const int w = tid >> 6, wy = w >> 1, wx = w & 1;
  const int col = lane & 15, quad = lane >> 4;

  const int r8 = tid >> 3, c8i = tid & 7;
  const int swz = (c8i ^ (r8 & 7)) * 8;       // (r8+p*32)&7 == r8&7
  const bf16* gA[4];
#pragma unroll
  for (int p = 0; p < 4; p++) {
    int ra = bm + r8 + p * 32;
    if (APAD) ra += (ra >> 11) * 3 + 3;
    gA[p] = A + (size_t)ra * lda + swz;
  }
  const bf16* gB[2];
#pragma unroll
  for (int p = 0; p < 2; p++)
    gB[p] = WT + (size_t)(bn + r8 + p * 32) * K + swz;

  f32x4 acc[4][2];
#pragma unroll
  for (int a = 0; a < 4; a++)
#pragma unroll
    for (int b = 0; b < 2; b++) acc[a][b] = (f32x4){0.f, 0.f, 0.f, 0.f};

  const int nsteps = K >> 6;                  // all K here are multiples of 64, nsteps >= 4

#define GSTAGE(buf, k0s)                                                       \
  do {                                                                         \
    bf16* dA = &smA[buf][tid * 8];                                             \
    gl16(gA[0] + (k0s), dA);                                                   \
    gl16(gA[1] + (k0s), dA + 2048);                                            \
    gl16(gA[2] + (k0s), dA + 4096);                                            \
    gl16(gA[3] + (k0s), dA + 6144);                                            \
    bf16* dB = &smB[buf][tid * 8];                                             \
    gl16(gB[0] + (k0s), dB);                                                   \
    gl16(gB[1] + (k0s), dB + 2048);                                            \
  } while (0)

  GSTAGE(0, 0);
  GSTAGE(1, 64);
  int buf = 0;
  for (int s = 0; s < nsteps; ++s) {
    if (s + 1 < nsteps) asm volatile("s_waitcnt vmcnt(6)" ::: "memory");
    else                asm volatile("s_waitcnt vmcnt(0)" ::: "memory");
    __builtin_amdgcn_s_barrier();
    if (s + 2 < nsteps) {
      int nb = buf + 2; if (nb >= 3) nb -= 3;
      GSTAGE(nb, (s + 2) * 64);
    }
    asm volatile("" ::: "memory");
    const bf16* bA = smA[buf];
    const bf16* bB = smB[buf];
#pragma unroll
    for (int kc = 0; kc < 2; kc++) {
      short8 af[4], bfr[2];
#pragma unroll
      for (int mt = 0; mt < 4; mt++) {
        const int row = wy * 64 + mt * 16 + col;
        af[mt] = *(const short8*)&bA[row * 64 + (((kc * 4 + quad) ^ (row & 7)) << 3)];
      }
#pragma unroll
      for (int nt = 0; nt < 2; nt++) {
        const int row = wx * 32 + nt * 16 + col;
        bfr[nt] = *(const short8*)&bB[row * 64 + (((kc * 4 + quad) ^ (row & 7)) << 3)];
      }
      __builtin_amdgcn_s_setprio(1);
#pragma unroll
      for (int mt = 0; mt < 4; mt++)
#pragma unroll
        for (int nt = 0; nt < 2; nt++)
          acc[mt][nt] = __builtin_amdgcn_mfma_f32_16x16x32_bf16(af[mt], bfr[nt], acc[mt][nt], 0, 0, 0);
      __builtin_amdgcn_s_setprio(0);
    }
    if (++buf >= 3) buf = 0;
  }
#undef GSTAGE

#pragma unroll
  for (int mt = 0; mt < 4; mt++) {
#pragma unroll
    for (int nt = 0; nt < 2; nt++) {
      const int n = bn + wx * 32 + nt * 16 + col;
      const int mrow0 = bm + wy * 64 + mt * 16 + quad * 4;
      float bs = bias ? bias[n] : 0.f;
      if (STORE == 1) {
        bf16* C = (bf16*)Cv + coff;
        ushort4 pk;
        pk.x = f2bu(acc[mt][nt][0] + bs); pk.y = f2bu(acc[mt][nt][1] + bs);
        pk.z = f2bu(acc[mt][nt][2] + bs); pk.w = f2bu(acc[mt][nt][3] + bs);
        *(ushort4*)(C + (size_t)n * 4096 + mrow0) = pk;
      } else if (STORE == 2) {
        float* O = (float*)Cv + coff;
#pragma unroll
        for (int r = 0; r < 4; r++) {
          size_t gi = (size_t)(mrow0 + r) * ldc + n;
          O[gi] = acc[mt][nt][r] + bs + xres[gi];
        }
      } else if (STORE == 3) {
        bf16* C = (bf16*)Cv;
        const int pr = (mrow0 >> 11) * 3 + 3;   // all 4 rows in same batch (128-blocks)
#pragma unroll
        for (int r = 0; r < 4; r++)
          C[(size_t)(mrow0 + pr + r) * ldc + n] = f2b(acc[mt][nt][r] + bs);
      } else {
        bf16* C = (bf16*)Cv + coff;
#pragma unroll
        for (int r = 0; r < 4; r++) {
          float v = acc[mt][nt][r] + bs;
          if (ACT == 1) v = v / (1.f + expf(-v));  // silu
          C[(size_t)(mrow0 + r) * ldc + n] = f2b(v);
        }
      }
    }
  }
}

// T1 bijective XCD swizzle (m204 form, r=0 case; requires nwg % 8 == 0).
__device__ __forceinline__ int xcd_work_id() {
  const int nx = gridDim.x, ny = gridDim.y;
  const int d = blockIdx.x + nx * (blockIdx.y + ny * blockIdx.z);
  const int q = (nx * ny * (int)gridDim.z) >> 3;
  return (d & 7) * q + (d >> 3);
}

// template variant (conv, fin). wx-FAST work-id order (round-9/13 form).
template <int ACT, int STORE, int APAD>
__global__ void __launch_bounds__(256) k_mgemm(const bf16* __restrict__ A, int lda,
                                               const bf16* __restrict__ WT,
                                               const float* __restrict__ bias,
                                               void* __restrict__ Cv,
                                               const float* __restrict__ xres,
                                               int ldc, int K,
                                               int gA, int gW, int gC) {
  const int wk = xcd_work_id();
  const int nx = gridDim.x, ny = gridDim.y;
  const int wx = wk % nx, rest = wk / nx;
  const int wy = rest % ny, g = rest / ny;
  mgemm_body(A + (size_t)g * gA, lda, WT + (size_t)g * gW, bias, Cv, xres,
             ldc, K, ACT, STORE, APAD, (size_t)g * gC, wy * 128, wx * 64);
}

// batched variant: z-slice selects one of 3 jobs (uniform scalar branches)
__global__ void __launch_bounds__(256) k_mgemmB(const bf16* A0, const bf16* A1, const bf16* A2,
                                                const bf16* W0, const bf16* W1, const bf16* W2,
                                                const float* b0, const float* b1, const float* b2,
                                                void* C0, void* C1, void* C2,
                                                int lda, int ldc, int K, int zPer,
                                                int gA, int gW, int gC,
                                                int actm, int storem, int apadm) {
  const int wk = xcd_work_id();
  const int nx = gridDim.x, ny = gridDim.y;
  const int wx = wk % nx, rest = wk / nx;
  const int wy = rest % ny, z = rest / ny;
  const int sel = z / zPer, zz = z % zPer;
  const bf16* A = (sel == 0 ? A0 : sel == 1 ? A1 : A2) + (size_t)zz * gA;
  const bf16* W = (sel == 0 ? W0 : sel == 1 ? W1 : W2) + (size_t)zz * gW;
  const float* bias = sel == 0 ? b0 : sel == 1 ? b1 : b2;
  void* Cv = sel == 0 ? C0 : sel == 1 ? C1 : C2;
  mgemm_body(A, lda, W, bias, Cv, nullptr, ldc, K,
             (actm >> sel) & 1, (storem >> (4 * sel)) & 15, (apadm >> sel) & 1,
             (size_t)zz * gC, wy * 128, wx * 64);
}

// ---------------- gate GEMV ----------------
__global__ void __launch_bounds__(256) k_gates(const bf16* __restrict__ q, const bf16* __restrict__ kk,
                                               const float* __restrict__ wi, const float* __restrict__ wib,
                                               const float* __restrict__ wf, const float* __restrict__ wfb,
                                               float* __restrict__ it, float* __restrict__ ft) {
  int gid  = blockIdx.x * 4 + (threadIdx.x >> 6);
  int lane = threadIdx.x & 63;
  int which = gid >> 12;
  int m = gid & 4095;
  const bf16* row = (which ? kk : q) + (size_t)m * DIM2X;
  const float* w = which ? wf : wi;
  float s[8] = {0, 0, 0, 0, 0, 0, 0, 0};
  for (int d = lane; d < DIM2X; d += 64) {
    float xv = b2f(row[d]);
    const float4* wp = (const float4*)(w + d * 8);
    float4 w0 = wp[0], w1 = wp[1];
    s[0] += xv * w0.x; s[1] += xv * w0.y; s[2] += xv * w0.z; s[3] += xv * w0.w;
    s[4] += xv * w1.x; s[5] += xv * w1.y; s[6] += xv * w1.z; s[7] += xv * w1.w;
  }
#pragma unroll
  for (int off = 32; off; off >>= 1) {
#pragma unroll
    for (int h = 0; h < 8; h++) s[h] += __shfl_xor(s[h], off);
  }
  if (lane == 0) {
    int b_ = m >> 11, tt = m & 2047;
    const float* wb = which ? wfb : wib;
    float* dst = which ? ft : it;
#pragma unroll
    for (int h = 0; h < 8; h++)
      dst[((size_t)(b_ * NHEADS + h)) * SEQ + tt] = s[h] + wb[h];
  }
}

// ---------------- per-(b,h) scan ----------------
__global__ void __launch_bounds__(256) k_scan(const float* __restrict__ it, const float* __restrict__ ft,
                                              float* __restrict__ cs, float* __restrict__ md) {
  const int bh = blockIdx.x;
  const int t  = threadIdx.x;
  const float* fr = ft + (size_t)bh * SEQ;
  const float* ir = it + (size_t)bh * SEQ;
  float* csr = cs + (size_t)bh * SEQ;
  float* mdr = md + (size_t)bh * SEQ;
  __shared__ float tmp[256];
  float loc[8]; float run = 0.f;
#pragma unroll
  for (int j = 0; j < 8; j++) {
    float xv = fr[t * 8 + j];
    float ls = fminf(xv, 0.f) - log1pf(expf(-fabsf(xv)));
    run += ls; loc[j] = run;
  }
  tmp[t] = run;
  __syncthreads();
  for (int off = 1; off < 256; off <<= 1) {
    float add = (t >= off) ? tmp[t - off] : 0.f;
    __syncthreads();
    tmp[t] += add;
    __syncthreads();
  }
  float exc = (t == 0) ? 0.f : tmp[t - 1];
  float csv[8];
#pragma unroll
  for (int j = 0; j < 8; j++) { csv[j] = loc[j] + exc; csr[t * 8 + j] = csv[j]; }
  __syncthreads();
  float rmax = -INFINITY; float gm[8];
#pragma unroll
  for (int j = 0; j < 8; j++) {
    float gv = ir[t * 8 + j] - csv[j];
    rmax = fmaxf(rmax, gv); gm[j] = rmax;
  }
  tmp[t] = rmax;
  __syncthreads();
  for (int off = 1; off < 256; off <<= 1) {
    float other = (t >= off) ? tmp[t - off] : -INFINITY;
    __syncthreads();
    tmp[t] = fmaxf(tmp[t], other);
    __syncthreads();
  }
  float emax = (t == 0) ? -INFINITY : tmp[t - 1];
#pragma unroll
  for (int j = 0; j < 8; j++) mdr[t * 8 + j] = csv[j] + fmaxf(gm[j], emax);
}

// ---------------- MFMA causal attention: 3-buffer pipeline + T5 setprio ----------------
// Single tile per block, grid (32,16). Stage-after-barrier 3-buffer pipeline, counted
// vmcnt(4/0). T5 setprio around MFMA clusters (round 14: 110.6 -> 101.8us, +8%).
// FUSED GroupNorm + skip/bgate epilogue writes PRE directly.
__global__ void __launch_bounds__(256) k_attn_mfma(const bf16* __restrict__ qh,
                                                   const bf16* __restrict__ kh,
                                                   const bf16* __restrict__ vt,
                                                   const float* __restrict__ cs,
                                                   const float* __restrict__ md,
                                                   const float* __restrict__ itl,
                                                   const bf16* __restrict__ qk,
                                                   const bf16* __restrict__ bg,
                                                   const float* __restrict__ gw,
                                                   const float* __restrict__ gb,
                                                   const float* __restrict__ skip,
                                                   bf16* __restrict__ pre) {
  const int bh = blockIdx.y, b_ = bh >> 3, h = bh & 7;
  const int bx = blockIdx.x;
  const int tile = ((blockIdx.y >> 3) & 1) ? bx : 31 - bx;   // balanced pairing heuristic
  const int i0 = tile * 64;
  const int tid = threadIdx.x;
  const int w = tid >> 6;                     // wave 0..3 -> i-rows i0+16w..
  const int lane = tid & 63;
  const int col = lane & 15, quad = lane >> 4;
  const int i0w = i0 + w * 16;
  const int iwmax = i0w + 15;
  const float L2E = 1.44269504f;

  __shared__ __align__(16) bf16 smK[3 * 4096]; // [buf][j 32][d 128], chunk^(j&7) swizzle
  __shared__ __align__(16) bf16 smV[3 * 4096]; // [buf][n 128][j 32], chunk^((n>>1)&3) swizzle
  __shared__ __align__(16) bf16 Sc[4][16][40];

  const size_t baseQK = ((size_t)b_ * SEQ) * DIM2X + (size_t)h * HDIM;
  const size_t vtb = (size_t)(h * HDIM) * 4096 + (size_t)b_ * SEQ;
  const float* csp = cs + (size_t)bh * SEQ;
  const float* mdp = md + (size_t)bh * SEQ;
  const float* itp = itl + (size_t)bh * SEQ;

  short8 qf[4];
#pragma unroll
  for (int kc = 0; kc < 4; kc++)
    qf[kc] = *(const short8*)(qh + baseQK + (size_t)(i0w + col) * DIM2X + kc * 32 + quad * 8);

  float cs_i[4], md_i[4];                     // log2 domain
#pragma unroll
  for (int r = 0; r < 4; r++) {
    int i = i0w + quad * 4 + r;
    cs_i[r] = csp[i] * L2E; md_i[r] = mdp[i] * L2E;
  }

  f32x4 accpv[8];
#pragma unroll
  for (int nb = 0; nb < 8; nb++) accpv[nb] = (f32x4){0.f, 0.f, 0.f, 0.f};
  float rs[4] = {0.f, 0.f, 0.f, 0.f};

  // staging sources (thread t covers LDS chunk t of each 8KB buffer; source pre-swizzled)
  const int kj = tid >> 4, kq = tid & 15;     // K: row kj (+16), chunk kq
  const bf16* gKs = kh + baseQK + (size_t)kj * DIM2X + ((kq ^ (kj & 7)) * 8);
  const int vn = tid >> 2, vq = tid & 3;      // V: row vn (+64), chunk vq
  const bf16* gVs = vt + vtb + (size_t)vn * 4096 + ((vq ^ ((vn >> 1) & 3)) * 8);

  const int trips = 2 * tile + 2;

#define STAGE(buf, j0s)                                                        \
  do {                                                                         \
    bf16* dK = &smK[(buf) * 4096 + tid * 8];                                   \
    gl16(gKs + (size_t)(j0s) * DIM2X, dK);                                     \
    gl16(gKs + (size_t)((j0s) + 16) * DIM2X, dK + 2048);                       \
    bf16* dV = &smV[(buf) * 4096 + tid * 8];                                   \
    gl16(gVs + (j0s), dV);                                                     \
    gl16(gVs + (j0s) + (size_t)64 * 4096, dV + 2048);                          \
  } while (0)

  STAGE(0, 0);
  STAGE(1, 32);                               // trips >= 2 always
  int cur = 0;
  for (int t = 0; t < trips; ++t) {
    const int j0p = t * 32;
    if (t + 1 < trips) asm volatile("s_waitcnt vmcnt(4)" ::: "memory");
    else               asm volatile("s_waitcnt vmcnt(0)" ::: "memory");
    __builtin_amdgcn_s_barrier();
    if (t + 2 < trips) {
      int nb = cur + 2; if (nb >= 3) nb -= 3;
      STAGE(nb, j0p + 64);
    }
    asm volatile("" ::: "memory");
    if (j0p <= iwmax) {
      // hoisted gate loads, log2 domain
      float g0 = (itp[j0p + col] - csp[j0p + col]) * L2E;
      float g1 = (itp[j0p + 16 + col] - csp[j0p + 16 + col]) * L2E;
      const bool jt1 = (j0p + 16 <= iwmax);
#pragma unroll
      for (int jt = 0; jt < 2; jt++) {
        const int j0 = j0p + jt * 16;
        float sv[4] = {0.f, 0.f, 0.f, 0.f};
        if (jt == 0 || jt1) {
          const int jj = jt * 16 + col;
          f32x4 aq = (f32x4){0.f, 0.f, 0.f, 0.f};
          __builtin_amdgcn_s_setprio(1);
#pragma unroll
          for (int kc = 0; kc < 4; kc++) {
            short8 bk = *(const short8*)&smK[cur * 4096 + jj * 128 + ((((kc << 2) | quad) ^ (jj & 7)) << 3)];
            aq = __builtin_amdgcn_mfma_f32_16x16x32_bf16(qf[kc], bk, aq, 0, 0, 0);
          }
          __builtin_amdgcn_s_setprio(0);
          const int j = j0 + col;
          const float gj = jt ? g1 : g0;
#pragma unroll
          for (int r = 0; r < 4; r++) {
            const int i = i0w + quad * 4 + r;
            // arg <= -5 by construction (md = exact row max); 2^-5 = 1/tau
            float s = (j <= i) ? exp2f(cs_i[r] + gj - md_i[r] - 5.f) * aq[r] : 0.f;
            sv[r] = s; rs[r] += s;
          }
        }
#pragma unroll
        for (int r = 0; r < 4; r++) Sc[w][quad * 4 + r][jt * 16 + col] = f2b(sv[r]);
      }
      // own-wave cross-lane LDS round-trip: force write completion before read (rule #18)
      asm volatile("s_waitcnt lgkmcnt(0)" ::: "memory");
      __builtin_amdgcn_sched_barrier(0);
      short8 af = *(const short8*)(&Sc[w][col][quad * 8]);
      __builtin_amdgcn_s_setprio(1);
#pragma unroll
      for (int nb = 0; nb < 8; nb++) {
        const int rn = nb * 16 + col;
        short8 bv = *(const short8*)&smV[cur * 4096 + rn * 32 + ((quad ^ ((rn >> 1) & 3)) << 3)];
        accpv[nb] = __builtin_amdgcn_mfma_f32_16x16x32_bf16(af, bv, accpv[nb], 0, 0, 0);
      }
      __builtin_amdgcn_s_setprio(0);
    }
    cur = (cur + 1 == 3) ? 0 : cur + 1;
  }
#undef STAGE

  // ---- fused epilogue: H normalize + GroupNorm + skip/bgate, write PRE ----
#pragma unroll
  for (int r = 0; r < 4; r++) {
    float v = rs[r];
    v += __shfl_xor(v, 1); v += __shfl_xor(v, 2);
    v += __shfl_xor(v, 4); v += __shfl_xor(v, 8);
    rs[r] = v;
  }
  float inv[4];
#pragma unroll
  for (int r = 0; r < 4; r++) {
    float maxit = fmaxf(fabsf(rs[r]), exp2f(fminf(-md_i[r], 43.f)));
    inv[r] = 1.f / (maxit + 1e-8f);
  }
  // per-col params (col = h*128 + nb*16 + colIdx; independent of r)
  float gwv[8], gbv[8], skv[8];
#pragma unroll
  for (int nb = 0; nb < 8; nb++) {
    int c = h * HDIM + nb * 16 + col;
    gwv[nb] = gw[c]; gbv[nb] = gb[c]; skv[nb] = skip[c];
  }
#pragma unroll
  for (int r = 0; r < 4; r++) {
    const int row = i0w + quad * 4 + r;       // row within batch
    float s1 = 0.f, s2 = 0.f;
#pragma unroll
    for (int nb = 0; nb < 8; nb++) {
      float v = accpv[nb][r] * inv[r];
      s1 += v; s2 += v * v;
    }
    // reduce over the 16 lanes of this quad-group (all 128 head-dims of this row)
    s1 += __shfl_xor(s1, 1); s2 += __shfl_xor(s2, 1);
    s1 += __shfl_xor(s1, 2); s2 += __shfl_xor(s2, 2);
    s1 += __shfl_xor(s1, 4); s2 += __shfl_xor(s2, 4);
    s1 += __shfl_xor(s1, 8); s2 += __shfl_xor(s2, 8);
    float mu  = s1 * (1.f / 128.f);
    float var = s2 * (1.f / 128.f) - mu * mu;
    float rsg = rsqrtf(var + EPSF);
    const size_t rbase = baseQK + (size_t)row * DIM2X;   // includes batch+head offset
#pragma unroll
    for (int nb = 0; nb < 8; nb++) {
      float hv = accpv[nb][r] * inv[r];
      float hn = (hv - mu) * rsg * gwv[nb] + gbv[nb];
      size_t gi = rbase + nb * 16 + col;
      pre[gi] = f2b((hn + skv[nb] * b2f(qk[gi])) * b2f(bg[gi]));
    }
  }
}

extern "C" void kernel_launch(void* const* d_in, const int* in_sizes, int n_in,
                              void* d_out, int out_size, void* d_ws, size_t ws_size,
                              hipStream_t stream) {
  const float* x     = (const float*)d_in[0];
  const float* ln_w  = (const float*)d_in[1];
  const float* ln_b  = (const float*)d_in[2];
  const float* mlp1w = (const float*)d_in[3];
  const float* mlp1b = (const float*)d_in[4];
  const float* mlp2w = (const float*)d_in[5];
  const float* mlp2b = (const float*)d_in[6];
  const float* convw = (const float*)d_in[7];
  const float* convb = (const float*)d_in[8];
  const float* bqw   = (const float*)d_in[9];
  const float* bkw   = (const float*)d_in[10];
  const float* bvw   = (const float*)d_in[11];
  const float* wqw   = (const float*)d_in[12];
  const float* wqb   = (const float*)d_in[13];
  const float* wkw   = (const float*)d_in[14];
  const float* wkb   = (const float*)d_in[15];
  const float* wvw   = (const float*)d_in[16];
  const float* wvb   = (const float*)d_in[17];
  const float* wiw   = (const float*)d_in[18];
  const float* wib   = (const float*)d_in[19];
  const float* wfw   = (const float*)d_in[20];
  const float* wfb   = (const float*)d_in[21];
  const float* gnw   = (const float*)d_in[22];
  const float* gnb   = (const float*)d_in[23];
  const float* skip  = (const float*)d_in[24];
  const float* finw  = (const float*)d_in[25];
  const float* finb  = (const float*)d_in[26];
  float* out = (float*)d_out;

  float* GA  = (float*)d_ws;
  float* ITb = GA;
  float* FTb = GA + 32768;
  float* CSb = GA + 65536;
  float* MDb = GA + 98304;
  const size_t SLOT = 4u * 1024u * 1024u;
  bf16* S0 = (bf16*)((char*)d_ws + (1 << 20));
  bf16* S1 = S0 + SLOT;
  bf16* S2 = S1 + SLOT;
  bf16* S3 = S2 + SLOT;
  bf16* S4 = S3 + SLOT;
  bf16* S5 = S4 + SLOT;
  bf16* S6 = S5 + SLOT;
  bf16 *LN = S0, *BG = S2, *QKb = S3, *Qb = S4, *Kb = S5, *Vb = S6;
  bf16 *QH = S0, *KH = S1, *VT = S4, *PRE = S6;
  bf16* WTb   = S6 + SLOT;
  bf16* mlp1T = WTb;
  bf16* mlp2T = WTb + 524288;
  bf16* convT = WTb + 1048576;                 // [1024][4096] flat-K layout
  bf16* bqT   = WTb + 5242880;
  bf16* bkT   = bqT + 262144;
  bf16* bvT   = bkT + 262144;
  bf16* wqT   = bvT + 262144;
  bf16* wkT   = wqT + 1048576;
  bf16* wvT   = wkT + 1048576;
  bf16* finT  = wvT + 1048576;
  bf16* APD   = finT + 524288;                 // padded A: [2][2051][1024]

  // fused weight prep
  k_castT3<<<dim3(32, 16, 2), 256, 0, stream>>>(mlp1w, mlp2w, mlp2w, mlp1T, DIMX, DIM2X, 1, 0, 524288);
  k_castT3<<<dim3(32, 32, 3), 256, 0, stream>>>(wqw, wkw, wvw, wqT, DIM2X, DIM2X, 1, 0, 1048576);
  k_castT3<<<dim3(8, 8, 12), 256, 0, stream>>>(bqw, bkw, bvw, bqT, 256, 256, 4, 65536, 65536);
  k_castT3<<<dim3(16, 32, 1), 256, 0, stream>>>(finw, finw, finw, finT, DIM2X, DIMX, 1, 0, 524288);
  k_convwT<<<4096, 256, 0, stream>>>(convw, convT);
  k_zeropad<<<24, 256, 0, stream>>>(APD);

  k_layernorm<<<1024, 256, 0, stream>>>(x, ln_w, ln_b, LN);
  // batched mlp: sel0 = mlp1 -> APD (store3), sel1 = mlp2 -> BG (store0, silu)
  k_mgemmB<<<dim3(16, 32, 2), 256, 0, stream>>>(LN, LN, LN, mlp1T, mlp2T, mlp2T,
                                                mlp1b, mlp2b, mlp2b, APD, BG, BG,
                                                DIMX, DIM2X, DIMX, 1, 0, 0, 0,
                                                /*actm*/ 0b10, /*storem*/ 3 | (0 << 4), /*apadm*/ 0);
  // causal conv1d == single GEMM: K=4096 contiguous window over padded rows t..t+3
  k_mgemm<1, 0, 0><<<dim3(16, 16, 2), 256, 0, stream>>>(APD, DIM2X, convT, convb, QKb, nullptr,
                                                        DIM2X, 4096, PADROWS * DIM2X, 0, SEQ * DIM2X);
  // batched block-diag q/k/v: 12 z-slices (3 weights x 4 groups)
  k_mgemmB<<<dim3(4, 32, 12), 256, 0, stream>>>(QKb, QKb, APD, bqT, bkT, bvT,
                                                nullptr, nullptr, nullptr, Qb, Kb, Vb,
                                                DIM2X, DIM2X, 256, 4, 256, 65536, 256,
                                                /*actm*/ 0, /*storem*/ 0, /*apadm*/ 0b100);
  k_gates<<<2048, 256, 0, stream>>>(Qb, Kb, wiw, wib, wfw, wfb, ITb, FTb);
  k_scan<<<16, 256, 0, stream>>>(ITb, FTb, CSb, MDb);
  // batched wq/wk/wv: sel2 writes V^T (store1)
  k_mgemmB<<<dim3(16, 32, 3), 256, 0, stream>>>(Qb, Kb, Vb, wqT, wkT, wvT,
                                                wqb, wkb, wvb, QH, KH, VT,
                                                DIM2X, DIM2X, DIM2X, 1, 0, 0, 0,
                                                /*actm*/ 0, /*storem*/ 0 | (0 << 4) | (1 << 8), /*apadm*/ 0);
  // attention with fused GroupNorm + skip/bgate epilogue (writes PRE directly)
  k_attn_mfma<<<dim3(32, 16), 256, 0, stream>>>(QH, KH, VT, CSb, MDb, ITb,
                                                QKb, BG, gnw, gnb, skip, PRE);
  k_mgemm<0, 2, 0><<<dim3(8, 32), 256, 0, stream>>>(PRE, DIM2X, finT, finb, out, x, DIMX, DIM2X, 0, 0, 0);
}